// Round 2
// baseline (699.174 us; speedup 1.0000x reference)
//
#include <hip/hip_runtime.h>
#include <hip/hip_bf16.h>

// Problem constants
#define B_  8192
#define L_  10
#define D_  128
#define H_  64
#define OUT_ 5

// ws float layout (all fp32):
#define WS_ENCW4   0                    // 192*256: [k][l][q] = encW[j=q*64+l][k]  (k<128: Wih, else Whh)
#define WS_ENCB4   49152                // 256:     [l][q] = bih[j]+bhh[j]
#define WS_DECW4   49408                // 69*256:  [k][l][q] = decW[j][k] (k<5: Wih, else Whh)
#define WS_DECB4   67072                // 256
#define WS_W1HC2   67328                // 64*64*2: [e][l][{W1h[l][e], W1c[l][e]}]
#define WS_W1XT    75520                // 64*64:   [e][l] = W1x[l][e]
#define WS_TOTAL   79616

__device__ __forceinline__ float sigmf(float x){ return 1.f/(1.f+__expf(-x)); }
__device__ __forceinline__ float tanhf_(float x){ return 1.f - 2.f/(1.f+__expf(2.f*x)); }
__device__ __forceinline__ float bcast(float v, int lane){
  return __uint_as_float(__builtin_amdgcn_readlane(__float_as_uint(v), lane));
}

__global__ void prep_kernel(const float* __restrict__ encWih, const float* __restrict__ encWhh,
                            const float* __restrict__ encbih, const float* __restrict__ encbhh,
                            const float* __restrict__ decWih, const float* __restrict__ decWhh,
                            const float* __restrict__ decbih, const float* __restrict__ decbhh,
                            const float* __restrict__ w1, float* __restrict__ ws)
{
  int stride = gridDim.x * blockDim.x;
  int tid0 = blockIdx.x * blockDim.x + threadIdx.x;
  for (int idx = tid0; idx < 192*256; idx += stride) {
    int k = idx >> 8, r = idx & 255, l = r >> 2, q = r & 3;
    int j = q*64 + l;
    float v = (k < 128) ? encWih[j*128 + k] : encWhh[j*64 + (k-128)];
    ws[WS_ENCW4 + idx] = v;
  }
  for (int idx = tid0; idx < 256; idx += stride) {
    int l = idx >> 2, q = idx & 3, j = q*64+l;
    ws[WS_ENCB4+idx] = encbih[j] + encbhh[j];
  }
  for (int idx = tid0; idx < 69*256; idx += stride) {
    int k = idx >> 8, r = idx & 255, l = r >> 2, q = r & 3, j = q*64+l;
    float v = (k < 5) ? decWih[j*5 + k] : decWhh[j*64 + (k-5)];
    ws[WS_DECW4 + idx] = v;
  }
  for (int idx = tid0; idx < 256; idx += stride) {
    int l = idx >> 2, q = idx & 3, j = q*64+l;
    ws[WS_DECB4+idx] = decbih[j] + decbhh[j];
  }
  for (int idx = tid0; idx < 64*64; idx += stride) {
    int e = idx >> 6, l = idx & 63;
    ws[WS_W1HC2 + (e*64+l)*2 + 0] = w1[l*192 + e];
    ws[WS_W1HC2 + (e*64+l)*2 + 1] = w1[l*192 + 64 + e];
    ws[WS_W1XT  + idx]            = w1[l*192 + 128 + e];
  }
}

#define R 4   // batch rows per wave

__global__ __launch_bounds__(256, 2) void darnn_kernel(
    const float* __restrict__ x, const float* __restrict__ y_hist,
    const float* __restrict__ h0e, const float* __restrict__ c0e,
    const float* __restrict__ h0d, const float* __restrict__ c0d,
    const float* __restrict__ enc_attn_w,
    const float* __restrict__ dec_attn_b1, const float* __restrict__ dec_attn_w2,
    const float* __restrict__ dec_attn_b2,
    const float* __restrict__ fc_w, const float* __restrict__ fc_b,
    const float* __restrict__ fcout_w, const float* __restrict__ fcout_b,
    const float* __restrict__ ws, float* __restrict__ out)
{
  __shared__ float xenc[4][R][L_][64];   // 40 KB, per-wave private slices
  const int wv = threadIdx.x >> 6;
  const int l  = threadIdx.x & 63;
  const int brow = blockIdx.x * (4*R) + wv*R;

  const float* encW4 = ws + WS_ENCW4;
  const float* decW4 = ws + WS_DECW4;

  float h[R], c[R];
  #pragma unroll
  for (int r=0;r<R;++r){
    h[r]=h0e[(brow+r)*64+l];
    c[r]=c0e[(brow+r)*64+l];
  }

  // Encoder input attention: at = softmax_d(score_x) (h/c/bias terms cancel in softmax)
  float at0[R], at1[R];
  {
    float wxv[L_];
    #pragma unroll
    for (int t=0;t<L_;++t) wxv[t]=enc_attn_w[2*H_ + t];
    #pragma unroll
    for (int r=0;r<R;++r){
      const float* xb = x + (size_t)(brow+r)*(L_*D_);
      float s0=0.f,s1=0.f;
      #pragma unroll
      for (int t=0;t<L_;++t){
        s0 += xb[t*D_+l]*wxv[t];
        s1 += xb[t*D_+64+l]*wxv[t];
      }
      float m = fmaxf(s0,s1);
      for (int o=32;o;o>>=1) m = fmaxf(m, __shfl_xor(m,o));
      float e0=__expf(s0-m), e1=__expf(s1-m);
      float ss=e0+e1;
      for (int o=32;o;o>>=1) ss += __shfl_xor(ss,o);
      float inv = 1.f/ss;
      at0[r]=e0*inv; at1[r]=e1*inv;
    }
  }

  // ---------------- Encoder ----------------
  for (int t=0;t<L_;++t){
    float wi0[R], wi1[R];
    #pragma unroll
    for (int r=0;r<R;++r){
      const float* xb = x + (size_t)(brow+r)*(L_*D_) + t*D_;
      wi0[r]=at0[r]*xb[l];
      wi1[r]=at1[r]*xb[64+l];
    }
    float4 bs = *(const float4*)(ws + WS_ENCB4 + l*4);
    float a0[R],a1[R],a2[R],a3[R];
    #pragma unroll
    for (int r=0;r<R;++r){ a0[r]=bs.x;a1[r]=bs.y;a2[r]=bs.z;a3[r]=bs.w; }
    #pragma unroll 4
    for (int d=0; d<64; ++d){
      float4 w = *(const float4*)(encW4 + (d*64+l)*4);
      #pragma unroll
      for (int r=0;r<R;++r){
        float v = bcast(wi0[r], d);
        a0[r]+=v*w.x; a1[r]+=v*w.y; a2[r]+=v*w.z; a3[r]+=v*w.w;
      }
    }
    #pragma unroll 4
    for (int d=0; d<64; ++d){
      float4 w = *(const float4*)(encW4 + ((64+d)*64+l)*4);
      #pragma unroll
      for (int r=0;r<R;++r){
        float v = bcast(wi1[r], d);
        a0[r]+=v*w.x; a1[r]+=v*w.y; a2[r]+=v*w.z; a3[r]+=v*w.w;
      }
    }
    #pragma unroll 4
    for (int e=0;e<64;++e){
      float4 w = *(const float4*)(encW4 + ((128+e)*64+l)*4);
      #pragma unroll
      for (int r=0;r<R;++r){
        float v = bcast(h[r], e);
        a0[r]+=v*w.x; a1[r]+=v*w.y; a2[r]+=v*w.z; a3[r]+=v*w.w;
      }
    }
    #pragma unroll
    for (int r=0;r<R;++r){
      float ig=sigmf(a0[r]), fg=sigmf(a1[r]), gg=tanhf_(a2[r]), og=sigmf(a3[r]);
      c[r]=fg*c[r]+ig*gg;
      h[r]=og*tanhf_(c[r]);
      xenc[wv][r][t][l]=h[r];
    }
  }

  // pre[r][lt][l] = sum_e xenc[r][lt][e] * W1x[l][e]
  float pre[R][L_];
  #pragma unroll
  for (int r=0;r<R;++r)
    #pragma unroll
    for (int lt=0;lt<L_;++lt) pre[r][lt]=0.f;
  for (int lt=0; lt<L_; ++lt){
    float xe[R];
    #pragma unroll
    for (int r=0;r<R;++r) xe[r]=xenc[wv][r][lt][l];
    #pragma unroll 4
    for (int e=0;e<64;++e){
      float w = ws[WS_W1XT + e*64+l];
      #pragma unroll
      for (int r=0;r<R;++r) pre[r][lt] += bcast(xe[r], e) * w;
    }
  }

  // ---------------- Decoder ----------------
  #pragma unroll
  for (int r=0;r<R;++r){
    h[r]=h0d[(brow+r)*64+l];
    c[r]=c0d[(brow+r)*64+l];
  }
  float b1l = dec_attn_b1[l];
  float w2l = dec_attn_w2[l];
  float b2  = dec_attn_b2[0];
  float ctx[R];
  #pragma unroll
  for (int r=0;r<R;++r) ctx[r]=0.f;

  for (int t=0;t<L_;++t){
    // vb[l] = b1[l] + sum_e h[e] W1h[l][e] + c[e] W1c[l][e]
    float vb[R];
    #pragma unroll
    for (int r=0;r<R;++r) vb[r]=b1l;
    #pragma unroll 4
    for (int e=0;e<64;++e){
      float2 w = *(const float2*)(ws + WS_W1HC2 + (e*64+l)*2);
      #pragma unroll
      for (int r=0;r<R;++r)
        vb[r] += bcast(h[r],e)*w.x + bcast(c[r],e)*w.y;
    }
    // scores -> softmax over L -> ctx, per row
    float yt[R][OUT_];
    #pragma unroll
    for (int r=0;r<R;++r){
      float sc[L_];
      #pragma unroll
      for (int lt=0;lt<L_;++lt){
        float z = tanhf_(pre[r][lt]+vb[r]);
        float p = z*w2l;
        for (int o=32;o;o>>=1) p += __shfl_xor(p,o);
        sc[lt]=p+b2;
      }
      float mx=sc[0];
      #pragma unroll
      for (int lt=1;lt<L_;++lt) mx=fmaxf(mx,sc[lt]);
      float ssum=0.f;
      #pragma unroll
      for (int lt=0;lt<L_;++lt){ sc[lt]=__expf(sc[lt]-mx); ssum+=sc[lt]; }
      float inv=1.f/ssum;
      float cx=0.f;
      #pragma unroll
      for (int lt=0;lt<L_;++lt) cx += sc[lt]*xenc[wv][r][lt][l];
      ctx[r]=cx*inv;
    }
    // y_tilde[o] = fc_b[o] + sum_e ctx[e] fc_w[o][e] + sum_j y_t[j] fc_w[o][64+j]
    #pragma unroll
    for (int r=0;r<R;++r){
      float yin[OUT_];
      #pragma unroll
      for (int j=0;j<OUT_;++j)
        yin[j]=y_hist[(size_t)(brow+r)*(L_*OUT_)+t*OUT_+j];
      #pragma unroll
      for (int o2=0;o2<OUT_;++o2){
        float p = ctx[r]*fc_w[o2*69+l];
        for (int o=32;o;o>>=1) p += __shfl_xor(p,o);
        p += fc_b[o2];
        #pragma unroll
        for (int j=0;j<OUT_;++j) p += yin[j]*fc_w[o2*69+64+j];
        yt[r][o2]=p;
      }
    }
    // gates
    float4 bs = *(const float4*)(ws + WS_DECB4 + l*4);
    float a0[R],a1[R],a2[R],a3[R];
    #pragma unroll
    for (int r=0;r<R;++r){ a0[r]=bs.x;a1[r]=bs.y;a2[r]=bs.z;a3[r]=bs.w; }
    #pragma unroll
    for (int k=0;k<OUT_;++k){
      float4 w = *(const float4*)(decW4 + (k*64+l)*4);
      #pragma unroll
      for (int r=0;r<R;++r){
        float v = yt[r][k];
        a0[r]+=v*w.x;a1[r]+=v*w.y;a2[r]+=v*w.z;a3[r]+=v*w.w;
      }
    }
    #pragma unroll 4
    for (int e=0;e<64;++e){
      float4 w = *(const float4*)(decW4 + ((5+e)*64+l)*4);
      #pragma unroll
      for (int r=0;r<R;++r){
        float v = bcast(h[r],e);
        a0[r]+=v*w.x;a1[r]+=v*w.y;a2[r]+=v*w.z;a3[r]+=v*w.w;
      }
    }
    #pragma unroll
    for (int r=0;r<R;++r){
      float ig=sigmf(a0[r]), fg=sigmf(a1[r]), gg=tanhf_(a2[r]), og=sigmf(a3[r]);
      c[r]=fg*c[r]+ig*gg;
      h[r]=og*tanhf_(c[r]);
    }
  }

  // out[b][o] = fcout_b[o] + sum_e h[e] fcout_w[o][e] + ctx[e] fcout_w[o][64+e]
  #pragma unroll
  for (int o2=0;o2<OUT_;++o2){
    float wa=fcout_w[o2*128+l];
    float wb=fcout_w[o2*128+64+l];
    float fb=fcout_b[o2];
    #pragma unroll
    for (int r=0;r<R;++r){
      float p = h[r]*wa + ctx[r]*wb;
      for (int o=32;o;o>>=1) p += __shfl_xor(p,o);
      if (l==o2) out[(size_t)(brow+r)*OUT_+o2] = p+fb;
    }
  }
}

extern "C" void kernel_launch(void* const* d_in, const int* in_sizes, int n_in,
                              void* d_out, int out_size, void* d_ws, size_t ws_size,
                              hipStream_t stream) {
  const float* x          = (const float*)d_in[0];
  const float* y_hist     = (const float*)d_in[1];
  const float* h0_enc     = (const float*)d_in[2];
  const float* c0_enc     = (const float*)d_in[3];
  const float* h0_dec     = (const float*)d_in[4];
  const float* c0_dec     = (const float*)d_in[5];
  const float* enc_attn_w = (const float*)d_in[6];
  const float* enc_Wih    = (const float*)d_in[8];
  const float* enc_Whh    = (const float*)d_in[9];
  const float* enc_bih    = (const float*)d_in[10];
  const float* enc_bhh    = (const float*)d_in[11];
  const float* dec_attn_w1= (const float*)d_in[12];
  const float* dec_attn_b1= (const float*)d_in[13];
  const float* dec_attn_w2= (const float*)d_in[14];
  const float* dec_attn_b2= (const float*)d_in[15];
  const float* dec_Wih    = (const float*)d_in[16];
  const float* dec_Whh    = (const float*)d_in[17];
  const float* dec_bih    = (const float*)d_in[18];
  const float* dec_bhh    = (const float*)d_in[19];
  const float* fc_w       = (const float*)d_in[20];
  const float* fc_b       = (const float*)d_in[21];
  const float* fcout_w    = (const float*)d_in[22];
  const float* fcout_b    = (const float*)d_in[23];
  float* ws = (float*)d_ws;
  float* out = (float*)d_out;

  hipLaunchKernelGGL(prep_kernel, dim3(128), dim3(256), 0, stream,
                     enc_Wih, enc_Whh, enc_bih, enc_bhh,
                     dec_Wih, dec_Whh, dec_bih, dec_bhh,
                     dec_attn_w1, ws);
  hipLaunchKernelGGL(darnn_kernel, dim3(B_/(4*R)), dim3(256), 0, stream,
                     x, y_hist, h0_enc, c0_enc, h0_dec, c0_dec,
                     enc_attn_w, dec_attn_b1, dec_attn_w2, dec_attn_b2,
                     fc_w, fc_b, fcout_w, fcout_b, ws, out);
}